// Round 2
// baseline (52.511 us; speedup 1.0000x reference)
//
#include <hip/hip_runtime.h>

#define BATCH 16
#define NUM_HEADS 32
#define NUM_KV 8
#define GQ 4            // query heads per kv head
#define HD 128
#define PAGE 256        // cache block size
#define MAXB 8
#define MAXCTX 2048
#define QSCALE 0.08838834764831845f

// ws layout per (b,kv,split): [4 m][4 l][4*128 acc] = 520 floats
#define WS_STRIDE 520

template <int NS>
__global__ __launch_bounds__(256, 4) void pa_partial(
    const float* __restrict__ q,
    const float* __restrict__ knew,
    const float* __restrict__ vnew,
    const float* __restrict__ kc,
    const float* __restrict__ vc,
    const int* __restrict__ block_tables,
    const int* __restrict__ context_lens,
    float* __restrict__ ws)
{
  constexpr int TPS = MAXCTX / NS;    // tokens per split
  int blk = blockIdx.x;
  int split = blk % NS;
  int kv = (blk / NS) & 7;
  int b = blk / (NS * NUM_KV);
  int ctx = context_lens[b];
  int start = split * TPS;
  if (start >= ctx) return;           // uniform over block
  int n = min(TPS, ctx - start);
  int page = block_tables[b * MAXB + (start >> 8)];
  int pbase = page * PAGE + (start & (PAGE - 1));   // first token's row in cache

  int tid = threadIdx.x;
  int w = tid >> 6;        // wave 0..3
  int lane = tid & 63;
  int grp = lane >> 4;     // 16-lane token group, 0..3
  int j = lane & 15;       // dim slice: dims [j*8, j*8+8)

  // load q for the 4 query heads of this kv head, pre-scaled
  float qr[GQ][8];
  #pragma unroll
  for (int g = 0; g < GQ; ++g) {
    const float* qp = q + ((size_t)(b * NUM_HEADS + kv * GQ + g)) * HD + j * 8;
    float4 a = *(const float4*)(qp);
    float4 c = *(const float4*)(qp + 4);
    qr[g][0]=a.x*QSCALE; qr[g][1]=a.y*QSCALE; qr[g][2]=a.z*QSCALE; qr[g][3]=a.w*QSCALE;
    qr[g][4]=c.x*QSCALE; qr[g][5]=c.y*QSCALE; qr[g][6]=c.z*QSCALE; qr[g][7]=c.w*QSCALE;
  }

  float m[GQ], l[GQ], acc[GQ][8];
  #pragma unroll
  for (int g = 0; g < GQ; ++g) {
    m[g] = -1e30f; l[g] = 0.f;
    #pragma unroll
    for (int e = 0; e < 8; ++e) acc[g][e] = 0.f;
  }

  const float* knew_row = knew + (size_t)(b * NUM_KV + kv) * HD;
  const float* vnew_row = vnew + (size_t)(b * NUM_KV + kv) * HD;

  int iters = (n + 15) >> 4;   // 16 tokens per block iteration (4 waves x 4 groups)
  int tbase = w * 4 + grp;     // this lane's token slot within an iteration

  // --- helpers as macros to keep everything in registers (no runtime-indexed arrays)
  #define LOADROW(KK, VV, I)                                              \
    {                                                                     \
      int tl = tbase + (I) * 16;                                          \
      int tlc = tl < n ? tl : 0;                                          \
      const float* krow; const float* vrow;                               \
      if (start + tlc == ctx - 1) { krow = knew_row; vrow = vnew_row; }   \
      else {                                                              \
        size_t off = ((size_t)(pbase + tlc) * NUM_KV + kv) * HD;          \
        krow = kc + off; vrow = vc + off;                                 \
      }                                                                   \
      float4 k0 = *(const float4*)(krow + j * 8);                         \
      float4 k1 = *(const float4*)(krow + j * 8 + 4);                     \
      float4 v0 = *(const float4*)(vrow + j * 8);                         \
      float4 v1 = *(const float4*)(vrow + j * 8 + 4);                     \
      KK[0]=k0.x; KK[1]=k0.y; KK[2]=k0.z; KK[3]=k0.w;                     \
      KK[4]=k1.x; KK[5]=k1.y; KK[6]=k1.z; KK[7]=k1.w;                     \
      VV[0]=v0.x; VV[1]=v0.y; VV[2]=v0.z; VV[3]=v0.w;                     \
      VV[4]=v1.x; VV[5]=v1.y; VV[6]=v1.z; VV[7]=v1.w;                     \
    }

  #define COMPUTE(KK, VV, I)                                              \
    {                                                                     \
      bool valid = (tbase + (I) * 16) < n;                                \
      _Pragma("unroll")                                                   \
      for (int g = 0; g < GQ; ++g) {                                      \
        float s = 0.f;                                                    \
        _Pragma("unroll")                                                 \
        for (int e = 0; e < 8; ++e) s += qr[g][e] * KK[e];                \
        s += __shfl_xor(s, 1);                                            \
        s += __shfl_xor(s, 2);                                            \
        s += __shfl_xor(s, 4);                                            \
        s += __shfl_xor(s, 8);                                            \
        if (valid) {                                                      \
          if (s > m[g]) {      /* rare: rescale history */                \
            float sc = __expf(m[g] - s);                                  \
            l[g] *= sc;                                                   \
            _Pragma("unroll")                                             \
            for (int e = 0; e < 8; ++e) acc[g][e] *= sc;                  \
            m[g] = s;                                                     \
          }                                                               \
          float p = __expf(s - m[g]);                                     \
          l[g] += p;                                                      \
          _Pragma("unroll")                                               \
          for (int e = 0; e < 8; ++e) acc[g][e] += p * VV[e];             \
        }                                                                 \
      }                                                                   \
    }

  float kA[8], vA[8], kB[8], vB[8];
  LOADROW(kA, vA, 0)
  for (int i = 0; i < iters; ) {
    if (i + 1 < iters) LOADROW(kB, vB, i + 1)
    COMPUTE(kA, vA, i)
    ++i; if (i >= iters) break;
    if (i + 1 < iters) LOADROW(kA, vA, i + 1)
    COMPUTE(kB, vB, i)
    ++i;
  }
  #undef LOADROW
  #undef COMPUTE

  // merge the 4 token-groups within each wave (butterfly over lane masks 16, 32)
  #pragma unroll
  for (int g = 0; g < GQ; ++g) {
    #pragma unroll
    for (int mask = 16; mask <= 32; mask <<= 1) {
      float mo = __shfl_xor(m[g], mask);
      float lo = __shfl_xor(l[g], mask);
      float mn = fmaxf(m[g], mo);
      float ea = __expf(m[g] - mn);
      float eb = __expf(mo   - mn);
      l[g] = l[g] * ea + lo * eb;
      #pragma unroll
      for (int e = 0; e < 8; ++e) {
        float ao = __shfl_xor(acc[g][e], mask);
        acc[g][e] = acc[g][e] * ea + ao * eb;
      }
      m[g] = mn;
    }
  }

  // cross-wave merge via LDS
  __shared__ float s_m[4][GQ], s_l[4][GQ];
  __shared__ float s_acc[4][GQ][HD];
  if (lane < 16) {
    #pragma unroll
    for (int g = 0; g < GQ; ++g) {
      #pragma unroll
      for (int e = 0; e < 8; ++e) s_acc[w][g][j * 8 + e] = acc[g][e];
      if (j == 0) { s_m[w][g] = m[g]; s_l[w][g] = l[g]; }
    }
  }
  __syncthreads();

  float* outp = ws + (size_t)((b * NUM_KV + kv) * NS + split) * WS_STRIDE;
  for (int idx = tid; idx < GQ * HD; idx += 256) {
    int g = idx >> 7;
    int d = idx & 127;
    float M = fmaxf(fmaxf(s_m[0][g], s_m[1][g]), fmaxf(s_m[2][g], s_m[3][g]));
    float e0 = __expf(s_m[0][g] - M);
    float e1 = __expf(s_m[1][g] - M);
    float e2 = __expf(s_m[2][g] - M);
    float e3 = __expf(s_m[3][g] - M);
    float A = s_acc[0][g][d]*e0 + s_acc[1][g][d]*e1 + s_acc[2][g][d]*e2 + s_acc[3][g][d]*e3;
    outp[8 + idx] = A;
    if (d == 0) {
      float Ls = s_l[0][g]*e0 + s_l[1][g]*e1 + s_l[2][g]*e2 + s_l[3][g]*e3;
      outp[g] = M;
      outp[GQ + g] = Ls;
    }
  }
}

template <int NS>
__global__ __launch_bounds__(128) void pa_reduce(
    const float* __restrict__ ws,
    const int* __restrict__ context_lens,
    float* __restrict__ out)
{
  constexpr int TPS = MAXCTX / NS;
  int blk = blockIdx.x;     // (b, kv, g)
  int g  = blk & 3;
  int kv = (blk >> 2) & 7;
  int b  = blk >> 5;
  int d  = threadIdx.x;
  int ctx = context_lens[b];
  int ns = (ctx + TPS - 1) / TPS;
  const float* base = ws + (size_t)((b * NUM_KV + kv) * NS) * WS_STRIDE;

  float M = -1e30f;
  for (int s = 0; s < ns; ++s) M = fmaxf(M, base[s * WS_STRIDE + g]);
  float Lsum = 0.f, A = 0.f;
  for (int s = 0; s < ns; ++s) {
    float e = __expf(base[s * WS_STRIDE + g] - M);
    Lsum += base[s * WS_STRIDE + GQ + g] * e;
    A    += base[s * WS_STRIDE + 8 + g * HD + d] * e;
  }
  out[((size_t)(b * NUM_HEADS) + kv * GQ + g) * HD + d] = A / Lsum;
}

extern "C" void kernel_launch(void* const* d_in, const int* in_sizes, int n_in,
                              void* d_out, int out_size, void* d_ws, size_t ws_size,
                              hipStream_t stream) {
  const float* q  = (const float*)d_in[0];
  const float* k  = (const float*)d_in[1];
  const float* v  = (const float*)d_in[2];
  const float* kc = (const float*)d_in[3];
  const float* vc = (const float*)d_in[4];
  const int* block_tables = (const int*)d_in[5];
  const int* context_lens = (const int*)d_in[6];
  // d_in[7] = slot_mapping: not needed (new-token position derived from context_lens)

  float* ws = (float*)d_ws;
  float* out = (float*)d_out;

  size_t need16 = (size_t)BATCH * NUM_KV * 16 * WS_STRIDE * sizeof(float);
  if (ws_size >= need16) {
    pa_partial<16><<<BATCH * NUM_KV * 16, 256, 0, stream>>>(
        q, k, v, kc, vc, block_tables, context_lens, ws);
    pa_reduce<16><<<BATCH * NUM_KV * GQ, 128, 0, stream>>>(ws, context_lens, out);
  } else {
    pa_partial<8><<<BATCH * NUM_KV * 8, 256, 0, stream>>>(
        q, k, v, kc, vc, block_tables, context_lens, ws);
    pa_reduce<8><<<BATCH * NUM_KV * GQ, 128, 0, stream>>>(ws, context_lens, out);
  }
}

// Round 3
// 44.324 us; speedup vs baseline: 1.1847x; 1.1847x over previous
//
#include <hip/hip_runtime.h>

#define BATCH 16
#define NUM_HEADS 32
#define NUM_KV 8
#define GQ 4            // query heads per kv head
#define HD 128
#define PAGE 256        // cache block size
#define MAXB 8
#define MAXCTX 2048
#define NS 8            // one split per page
#define TPS 256         // tokens per split (== PAGE)
#define QSCALE 0.08838834764831845f

// ws layout per (b,kv,split): [4 M][4 l][4*128 acc] = 520 floats
#define WS_STRIDE 520

__global__ __launch_bounds__(256) void pa_partial(
    const float* __restrict__ q,
    const float* __restrict__ knew,
    const float* __restrict__ vnew,
    const float* __restrict__ kc,
    const float* __restrict__ vc,
    const int* __restrict__ block_tables,
    const int* __restrict__ context_lens,
    float* __restrict__ ws)
{
  int blk = blockIdx.x;
  int split = blk & (NS - 1);
  int kvh = (blk >> 3) & (NUM_KV - 1);
  int b = blk >> 6;
  int ctx = context_lens[b];
  int start = split * TPS;
  if (start >= ctx) return;            // uniform over block
  int n = min(TPS, ctx - start);
  int page = block_tables[b * MAXB + split];
  int pbase = page * PAGE;

  int tid = threadIdx.x;
  int w = tid >> 6;       // wave 0..3
  int lane = tid & 63;
  int grp = lane >> 4;    // 16-lane token group
  int j = lane & 15;      // dim slice [j*8, j*8+8)
  int tb = w * 4 + grp;   // token slot within an iteration (16 tokens/iter/block)

  __shared__ float s_p[GQ][TPS + 4];   // scores, then p = exp(s-M); stride 260 breaks bank aliasing
  __shared__ float s_red[4][GQ];
  __shared__ float s_Ml[2][GQ];
  __shared__ float s_acc[4][GQ][HD];

  // q for this kv head's 4 query heads, pre-scaled
  float qr[GQ][8];
  #pragma unroll
  for (int g = 0; g < GQ; ++g) {
    const float* qp = q + ((size_t)(b * NUM_HEADS + kvh * GQ + g)) * HD + j * 8;
    float4 a = *(const float4*)(qp);
    float4 c = *(const float4*)(qp + 4);
    qr[g][0]=a.x*QSCALE; qr[g][1]=a.y*QSCALE; qr[g][2]=a.z*QSCALE; qr[g][3]=a.w*QSCALE;
    qr[g][4]=c.x*QSCALE; qr[g][5]=c.y*QSCALE; qr[g][6]=c.z*QSCALE; qr[g][7]=c.w*QSCALE;
  }

  const float* knew_row = knew + (size_t)(b * NUM_KV + kvh) * HD;
  const float* vnew_row = vnew + (size_t)(b * NUM_KV + kvh) * HD;

  int iters = (n + 15) >> 4;

  // ---------- phase 1: all scores of the split (independent iterations) ----------
  #pragma unroll 2
  for (int i = 0; i < iters; ++i) {
    int tl = tb + i * 16;
    int tlc = tl < n ? tl : 0;
    const float* krow = (start + tlc == ctx - 1) ? knew_row
        : kc + ((size_t)(pbase + tlc) * NUM_KV + kvh) * HD;
    float4 k0 = *(const float4*)(krow + j * 8);
    float4 k1 = *(const float4*)(krow + j * 8 + 4);
    float kk[8] = {k0.x,k0.y,k0.z,k0.w,k1.x,k1.y,k1.z,k1.w};
    float s0 = 0.f, s1 = 0.f, s2 = 0.f, s3 = 0.f;
    #pragma unroll
    for (int e = 0; e < 8; ++e) {
      s0 += qr[0][e] * kk[e];
      s1 += qr[1][e] * kk[e];
      s2 += qr[2][e] * kk[e];
      s3 += qr[3][e] * kk[e];
    }
    #pragma unroll
    for (int mask = 1; mask <= 8; mask <<= 1) {
      s0 += __shfl_xor(s0, mask);
      s1 += __shfl_xor(s1, mask);
      s2 += __shfl_xor(s2, mask);
      s3 += __shfl_xor(s3, mask);
    }
    if (j < 4) {
      float val = (j == 0) ? s0 : (j == 1) ? s1 : (j == 2) ? s2 : s3;
      s_p[j][tl] = val;     // garbage at tl>=n is masked in phase 2
    }
  }
  __syncthreads();

  // ---------- phase 2: block-wide max, exp, sum (t = tid) ----------
  int t = tid;
  float sv[GQ], M[GQ], pv[GQ];
  #pragma unroll
  for (int g = 0; g < GQ; ++g) {
    sv[g] = (t < n) ? s_p[g][t] : -1e30f;
    float x = sv[g];
    #pragma unroll
    for (int mask = 1; mask <= 32; mask <<= 1) x = fmaxf(x, __shfl_xor(x, mask));
    M[g] = x;
  }
  if (lane == 0) {
    #pragma unroll
    for (int g = 0; g < GQ; ++g) s_red[w][g] = M[g];
  }
  __syncthreads();
  #pragma unroll
  for (int g = 0; g < GQ; ++g) {
    M[g] = fmaxf(fmaxf(s_red[0][g], s_red[1][g]), fmaxf(s_red[2][g], s_red[3][g]));
    pv[g] = __expf(sv[g] - M[g]);      // 0 for invalid t
    s_p[g][t] = pv[g];
  }
  __syncthreads();                      // s_p(p) visible; s_red reusable
  float lsum[GQ];
  #pragma unroll
  for (int g = 0; g < GQ; ++g) {
    float x = pv[g];
    #pragma unroll
    for (int mask = 1; mask <= 32; mask <<= 1) x += __shfl_xor(x, mask);
    lsum[g] = x;
  }
  if (lane == 0) {
    #pragma unroll
    for (int g = 0; g < GQ; ++g) s_red[w][g] = lsum[g];
  }
  __syncthreads();
  if (tid < GQ) {
    float Mv = (tid == 0) ? M[0] : (tid == 1) ? M[1] : (tid == 2) ? M[2] : M[3];
    s_Ml[0][tid] = Mv;
    s_Ml[1][tid] = s_red[0][tid] + s_red[1][tid] + s_red[2][tid] + s_red[3][tid];
  }

  // ---------- phase 3: PV accumulate (independent iterations, no shfl/exp) ----------
  float acc[GQ][8];
  #pragma unroll
  for (int g = 0; g < GQ; ++g)
    #pragma unroll
    for (int e = 0; e < 8; ++e) acc[g][e] = 0.f;

  #pragma unroll 2
  for (int i = 0; i < iters; ++i) {
    int tl = tb + i * 16;
    int tlc = tl < n ? tl : 0;
    const float* vrow = (start + tlc == ctx - 1) ? vnew_row
        : vc + ((size_t)(pbase + tlc) * NUM_KV + kvh) * HD;
    float4 v0 = *(const float4*)(vrow + j * 8);
    float4 v1 = *(const float4*)(vrow + j * 8 + 4);
    float vv[8] = {v0.x,v0.y,v0.z,v0.w,v1.x,v1.y,v1.z,v1.w};
    float p0 = s_p[0][tl];   // p==0 for tl>=n
    float p1 = s_p[1][tl];
    float p2 = s_p[2][tl];
    float p3 = s_p[3][tl];
    #pragma unroll
    for (int e = 0; e < 8; ++e) {
      acc[0][e] += p0 * vv[e];
      acc[1][e] += p1 * vv[e];
      acc[2][e] += p2 * vv[e];
      acc[3][e] += p3 * vv[e];
    }
  }

  // ---------- phase 4: additive merge across 16 groups ----------
  #pragma unroll
  for (int g = 0; g < GQ; ++g)
    #pragma unroll
    for (int e = 0; e < 8; ++e) {
      acc[g][e] += __shfl_xor(acc[g][e], 16);
      acc[g][e] += __shfl_xor(acc[g][e], 32);
    }
  if (lane < 16) {
    #pragma unroll
    for (int g = 0; g < GQ; ++g)
      #pragma unroll
      for (int e = 0; e < 8; ++e) s_acc[w][g][j * 8 + e] = acc[g][e];
  }
  __syncthreads();

  float* outp = ws + (size_t)((b * NUM_KV + kvh) * NS + split) * WS_STRIDE;
  for (int idx = tid; idx < GQ * HD; idx += 256) {
    int g = idx >> 7;
    int d = idx & 127;
    float A = s_acc[0][g][d] + s_acc[1][g][d] + s_acc[2][g][d] + s_acc[3][g][d];
    outp[8 + idx] = A;
    if (d == 0) {
      outp[g] = s_Ml[0][g];
      outp[GQ + g] = s_Ml[1][g];
    }
  }
}

__global__ __launch_bounds__(128) void pa_reduce(
    const float* __restrict__ ws,
    const int* __restrict__ context_lens,
    float* __restrict__ out)
{
  int blk = blockIdx.x;     // (b, kv, g)
  int g  = blk & 3;
  int kv = (blk >> 2) & 7;
  int b  = blk >> 5;
  int d  = threadIdx.x;
  int ctx = context_lens[b];
  int ns = (ctx + TPS - 1) / TPS;
  const float* base = ws + (size_t)((b * NUM_KV + kv) * NS) * WS_STRIDE;

  float M = -1e30f;
  for (int s = 0; s < ns; ++s) M = fmaxf(M, base[s * WS_STRIDE + g]);
  float Lsum = 0.f, A = 0.f;
  for (int s = 0; s < ns; ++s) {
    float e = __expf(base[s * WS_STRIDE + g] - M);
    Lsum += base[s * WS_STRIDE + GQ + g] * e;
    A    += base[s * WS_STRIDE + 8 + g * HD + d] * e;
  }
  out[((size_t)(b * NUM_HEADS) + kv * GQ + g) * HD + d] = A / Lsum;
}

extern "C" void kernel_launch(void* const* d_in, const int* in_sizes, int n_in,
                              void* d_out, int out_size, void* d_ws, size_t ws_size,
                              hipStream_t stream) {
  const float* q  = (const float*)d_in[0];
  const float* k  = (const float*)d_in[1];
  const float* v  = (const float*)d_in[2];
  const float* kc = (const float*)d_in[3];
  const float* vc = (const float*)d_in[4];
  const int* block_tables = (const int*)d_in[5];
  const int* context_lens = (const int*)d_in[6];
  // d_in[7] = slot_mapping: not needed (new-token position derived from context_lens)

  float* ws = (float*)d_ws;
  float* out = (float*)d_out;

  pa_partial<<<BATCH * NUM_KV * NS, 256, 0, stream>>>(
      q, k, v, kc, vc, block_tables, context_lens, ws);
  pa_reduce<<<BATCH * NUM_KV * GQ, 128, 0, stream>>>(ws, context_lens, out);
}